// Round 1
// baseline (501.326 us; speedup 1.0000x reference)
//
#include <hip/hip_runtime.h>

#define EPSF 1e-5f

// ---------------- helpers ----------------
__device__ __forceinline__ float wred(float v) {
#pragma unroll
  for (int off = 32; off > 0; off >>= 1) v += __shfl_down(v, off, 64);
  return v;
}

// ---------------- conv1: [32,1,20813,3] * [3,1,409,3] s=(6,1) -> [32,3,3401] + stats ----------------
// flat per batch: out[c][oh] = sum_i w[c][i] * mesh[oh*18 + i], i<1227
__global__ __launch_bounds__(256) void k_conv1(
    const float* __restrict__ mesh, const float* __restrict__ cw,
    const float* __restrict__ cb, float* __restrict__ out,
    float* __restrict__ part) {
  __shared__ float sm[5824];
  __shared__ float redm[4][6];
  const int tid = threadIdx.x;
  const int tile = blockIdx.x % 14, b = blockIdx.x / 14;
  const int oh0 = tile << 8;
  const int nvalid = min(256, 3401 - oh0);
  const int nload = (nvalid - 1) * 18 + 1227;
  const float* src = mesh + b * 62439 + oh0 * 18;
  for (int j = tid; j < nload; j += 256) sm[j] = src[j];
  __syncthreads();
  float a0 = 0.f, a1 = 0.f, a2 = 0.f;
  const float* xp = sm + tid * 18;
#pragma unroll 4
  for (int i = 0; i < 1226; i += 2) {
    float2 x = *(const float2*)(xp + i);
    a0 = fmaf(cw[i], x.x, fmaf(cw[i + 1], x.y, a0));
    a1 = fmaf(cw[1227 + i], x.x, fmaf(cw[1228 + i], x.y, a1));
    a2 = fmaf(cw[2454 + i], x.x, fmaf(cw[2455 + i], x.y, a2));
  }
  {
    float x = xp[1226];
    a0 = fmaf(cw[1226], x, a0);
    a1 = fmaf(cw[2453], x, a1);
    a2 = fmaf(cw[3680], x, a2);
  }
  a0 += cb[0]; a1 += cb[1]; a2 += cb[2];
  float st[6] = {0.f, 0.f, 0.f, 0.f, 0.f, 0.f};
  if (tid < nvalid) {
    const int oh = oh0 + tid;
    float* op = out + b * 10203 + oh;
    op[0] = a0; op[3401] = a1; op[6802] = a2;
    st[0] = a0; st[1] = a0 * a0; st[2] = a1; st[3] = a1 * a1; st[4] = a2; st[5] = a2 * a2;
  }
  const int lane = tid & 63, wid = tid >> 6;
#pragma unroll
  for (int c = 0; c < 6; ++c) {
    float rv = wred(st[c]);
    if (lane == 0) redm[wid][c] = rv;
  }
  __syncthreads();
  if (tid < 6)
    part[blockIdx.x * 6 + tid] = redm[0][tid] + redm[1][tid] + redm[2][tid] + redm[3][tid];
}

// ---------------- conv2: bn1(conv1) reshaped, 990-tap stride-3 -> [32,3,3072] + stats ----------------
__global__ __launch_bounds__(256) void k_conv2(
    const float* __restrict__ x1, const float* __restrict__ part1,
    const float* __restrict__ g1, const float* __restrict__ be1,
    const float* __restrict__ cw, const float* __restrict__ cb,
    float* __restrict__ out, float* __restrict__ part) {
  __shared__ float sm[1760];
  __shared__ float redm[4][6];
  __shared__ float coef[6];
  const int tid = threadIdx.x;
  const int lane = tid & 63, wid = tid >> 6;
  {  // reduce conv1 stats (448 blocks x 6) -> bn1 coefficients
    float r[6] = {0.f, 0.f, 0.f, 0.f, 0.f, 0.f};
    for (int j = tid; j < 448; j += 256) {
#pragma unroll
      for (int c = 0; c < 6; ++c) r[c] += part1[j * 6 + c];
    }
#pragma unroll
    for (int c = 0; c < 6; ++c) {
      float rv = wred(r[c]);
      if (lane == 0) redm[wid][c] = rv;
    }
    __syncthreads();
    if (tid == 0) {
      const float inv_n = 1.f / (32.f * 3401.f);
#pragma unroll
      for (int c = 0; c < 3; ++c) {
        float s = redm[0][2 * c] + redm[1][2 * c] + redm[2][2 * c] + redm[3][2 * c];
        float ss = redm[0][2 * c + 1] + redm[1][2 * c + 1] + redm[2][2 * c + 1] + redm[3][2 * c + 1];
        float m = s * inv_n;
        float var = ss * inv_n - m * m;
        float a = g1[c] * rsqrtf(var + EPSF);
        coef[c] = a; coef[3 + c] = be1[c] - m * a;
      }
    }
    __syncthreads();
  }
  const int tile = blockIdx.x % 12, b = blockIdx.x / 12;
  const int oh0 = tile << 8;
  const int g0 = oh0 * 3;
  const float* src = x1 + b * 10203 + g0;
  for (int j = tid; j < 1755; j += 256) {
    int gg = g0 + j;
    int c = (gg >= 6802) ? 2 : ((gg >= 3401) ? 1 : 0);
    sm[j] = fmaf(coef[c], src[j], coef[3 + c]);
  }
  __syncthreads();
  float a0 = 0.f, a1 = 0.f, a2 = 0.f;
  const float* xp = sm + tid * 3;
#pragma unroll 4
  for (int i = 0; i < 990; i += 2) {
    float x0 = xp[i], x1v = xp[i + 1];
    a0 = fmaf(cw[i], x0, fmaf(cw[i + 1], x1v, a0));
    a1 = fmaf(cw[990 + i], x0, fmaf(cw[991 + i], x1v, a1));
    a2 = fmaf(cw[1980 + i], x0, fmaf(cw[1981 + i], x1v, a2));
  }
  a0 += cb[0]; a1 += cb[1]; a2 += cb[2];
  const int oh = oh0 + tid;
  float* op = out + b * 9216 + oh;
  op[0] = a0; op[3072] = a1; op[6144] = a2;
  float st[6] = {a0, a0 * a0, a1, a1 * a1, a2, a2 * a2};
  __syncthreads();
#pragma unroll
  for (int c = 0; c < 6; ++c) {
    float rv = wred(st[c]);
    if (lane == 0) redm[wid][c] = rv;
  }
  __syncthreads();
  if (tid < 6)
    part[blockIdx.x * 6 + tid] = redm[0][tid] + redm[1][tid] + redm[2][tid] + redm[3][tid];
}

// ---------------- qkv: bn2 + prelu + 3x (9->4) ; q scaled by 1/sqrt(2)*log2(e) ----------------
__global__ __launch_bounds__(256) void k_qkv(
    const float* __restrict__ x2, const float* __restrict__ part2,
    const float* __restrict__ g2, const float* __restrict__ be2,
    const float* __restrict__ pa_p,
    const float* __restrict__ wq, const float* __restrict__ bq,
    const float* __restrict__ wk, const float* __restrict__ bk,
    const float* __restrict__ wv, const float* __restrict__ bv,
    float* __restrict__ qo, float* __restrict__ ko, float* __restrict__ vo) {
  __shared__ float redm[4][6];
  __shared__ float coef[6];
  const int tid = threadIdx.x;
  const int lane = tid & 63, wid = tid >> 6;
  {
    float r[6] = {0.f, 0.f, 0.f, 0.f, 0.f, 0.f};
    for (int j = tid; j < 384; j += 256) {
#pragma unroll
      for (int c = 0; c < 6; ++c) r[c] += part2[j * 6 + c];
    }
#pragma unroll
    for (int c = 0; c < 6; ++c) {
      float rv = wred(r[c]);
      if (lane == 0) redm[wid][c] = rv;
    }
    __syncthreads();
    if (tid == 0) {
      const float inv_n = 1.f / (32.f * 3072.f);
#pragma unroll
      for (int c = 0; c < 3; ++c) {
        float s = redm[0][2 * c] + redm[1][2 * c] + redm[2][2 * c] + redm[3][2 * c];
        float ss = redm[0][2 * c + 1] + redm[1][2 * c + 1] + redm[2][2 * c + 1] + redm[3][2 * c + 1];
        float m = s * inv_n;
        float var = ss * inv_n - m * m;
        float a = g2[c] * rsqrtf(var + EPSF);
        coef[c] = a; coef[3 + c] = be2[c] - m * a;
      }
    }
    __syncthreads();
  }
  const float pa = pa_p[0];
  const int id = blockIdx.x * 256 + tid;
  const int b = id >> 10, f = id & 1023;
  const float* src = x2 + b * 9216 + f * 9;
  float x[9];
  const int z0 = f * 9;
#pragma unroll
  for (int j = 0; j < 9; ++j) {
    int z = z0 + j;
    int c = (z >= 6144) ? 2 : ((z >= 3072) ? 1 : 0);
    float v = fmaf(coef[c], src[j], coef[3 + c]);
    x[j] = (v >= 0.f) ? v : pa * v;
  }
  const float QSCALE = 0.70710678118654752f * 1.44269504088896341f;  // 1/sqrt(HD) * log2(e)
#pragma unroll
  for (int dd = 0; dd < 4; ++dd) {
    float q = bq[dd], k = bk[dd], v = bv[dd];
#pragma unroll
    for (int j = 0; j < 9; ++j) {
      q = fmaf(wq[dd * 9 + j], x[j], q);
      k = fmaf(wk[dd * 9 + j], x[j], k);
      v = fmaf(wv[dd * 9 + j], x[j], v);
    }
    int hh = dd >> 1, d = dd & 1;
    int idx = ((b * 2 + hh) * 1024 + f) * 2 + d;
    qo[idx] = q * QSCALE;
    ko[idx] = k;
    vo[idx] = v;
  }
}

// ---------------- attention: per (b,h) 1024x1024 softmax(qk)v, HD=2 ----------------
__global__ __launch_bounds__(256) void k_attn(
    const float* __restrict__ q, const float* __restrict__ k,
    const float* __restrict__ v, float* __restrict__ av) {
  __shared__ float4 kv[1024];
  const int tid = threadIdx.x;
  const int bh = blockIdx.x >> 2, rq = blockIdx.x & 3;
  const float2* kp = (const float2*)(k + bh * 2048);
  const float2* vp = (const float2*)(v + bh * 2048);
  for (int j = tid; j < 1024; j += 256) {
    float2 kk = kp[j], vv = vp[j];
    kv[j] = make_float4(kk.x, kk.y, vv.x, vv.y);
  }
  __syncthreads();
  const int f = rq * 256 + tid;
  const float2 qv = *(const float2*)(q + (bh * 1024 + f) * 2);
  float m = -1e30f;
#pragma unroll 4
  for (int j = 0; j < 1024; ++j) {
    float4 kk = kv[j];
    m = fmaxf(m, fmaf(qv.x, kk.x, qv.y * kk.y));
  }
  float l = 0.f, o0 = 0.f, o1 = 0.f;
#pragma unroll 4
  for (int j = 0; j < 1024; ++j) {
    float4 kk = kv[j];
    float p = exp2f(fmaf(qv.x, kk.x, qv.y * kk.y) - m);  // q already in exp2 space
    l += p;
    o0 = fmaf(p, kk.z, o0);
    o1 = fmaf(p, kk.w, o1);
  }
  const float rl = 1.f / l;
  const int b = bh >> 1, hh = bh & 1;
  *(float2*)(av + b * 4096 + f * 4 + hh * 2) = make_float2(o0 * rl, o1 * rl);
}

// ---------------- fc: [32,4096] x [1024,4096]^T, K-split partials ----------------
// grid 256 = 8 o-blocks x 32 k-splits; tile 128o x 32b; thread = 4o x 4b
__global__ __launch_bounds__(256) void k_fc(
    const float* __restrict__ x, const float* __restrict__ w,
    float* __restrict__ pout) {
  __shared__ float xs[128 * 36];
  const int tid = threadIdx.x;
  const int ob = blockIdx.x & 7, ksp = blockIdx.x >> 3;
  const int k0 = ksp * 128, obase = ob * 128;
  for (int r = tid; r < 4096; r += 256) {
    int b = r >> 7, kk = r & 127;
    xs[kk * 36 + b] = x[b * 4096 + k0 + kk];
  }
  __syncthreads();
  const int og = tid & 31, bg = tid >> 5;
  const int o = obase + og * 4, bb0 = bg * 4;
  float acc[4][4] = {};
  const float* wp = w + o * 4096 + k0;
  for (int kk = 0; kk < 128; kk += 4) {
    float4 x0 = *(const float4*)&xs[(kk + 0) * 36 + bb0];
    float4 x1 = *(const float4*)&xs[(kk + 1) * 36 + bb0];
    float4 x2 = *(const float4*)&xs[(kk + 2) * 36 + bb0];
    float4 x3 = *(const float4*)&xs[(kk + 3) * 36 + bb0];
#pragma unroll
    for (int oo = 0; oo < 4; ++oo) {
      float4 wv = *(const float4*)(wp + oo * 4096 + kk);
      acc[oo][0] = fmaf(wv.x, x0.x, fmaf(wv.y, x1.x, fmaf(wv.z, x2.x, fmaf(wv.w, x3.x, acc[oo][0]))));
      acc[oo][1] = fmaf(wv.x, x0.y, fmaf(wv.y, x1.y, fmaf(wv.z, x2.y, fmaf(wv.w, x3.y, acc[oo][1]))));
      acc[oo][2] = fmaf(wv.x, x0.z, fmaf(wv.y, x1.z, fmaf(wv.z, x2.z, fmaf(wv.w, x3.z, acc[oo][2]))));
      acc[oo][3] = fmaf(wv.x, x0.w, fmaf(wv.y, x1.w, fmaf(wv.z, x2.w, fmaf(wv.w, x3.w, acc[oo][3]))));
    }
  }
#pragma unroll
  for (int bi = 0; bi < 4; ++bi) {
    float4 rv = make_float4(acc[0][bi], acc[1][bi], acc[2][bi], acc[3][bi]);
    *(float4*)&pout[(ksp * 32 + bb0 + bi) * 1024 + o] = rv;
  }
}

// ---------------- ff1: h=reduce(p_fc)+fc_b on the fly; [32,1024]x[1024,1024]^T ----------------
// grid 128 = 8 o-blocks x 16 k-splits; chunk 64
__global__ __launch_bounds__(256) void k_ff1(
    const float* __restrict__ pfc, const float* __restrict__ fcb,
    const float* __restrict__ w, float* __restrict__ pout) {
  __shared__ float xs[64 * 36];
  const int tid = threadIdx.x;
  const int ob = blockIdx.x & 7, ksp = blockIdx.x >> 3;
  const int k0 = ksp * 64, obase = ob * 128;
  for (int r = tid; r < 2048; r += 256) {
    int b = r >> 6, kk = r & 63;
    float hv = fcb[k0 + kk];
#pragma unroll 4
    for (int j = 0; j < 32; ++j) hv += pfc[(j * 32 + b) * 1024 + k0 + kk];
    xs[kk * 36 + b] = hv;
  }
  __syncthreads();
  const int og = tid & 31, bg = tid >> 5;
  const int o = obase + og * 4, bb0 = bg * 4;
  float acc[4][4] = {};
  const float* wp = w + o * 1024 + k0;
  for (int kk = 0; kk < 64; kk += 4) {
    float4 x0 = *(const float4*)&xs[(kk + 0) * 36 + bb0];
    float4 x1 = *(const float4*)&xs[(kk + 1) * 36 + bb0];
    float4 x2 = *(const float4*)&xs[(kk + 2) * 36 + bb0];
    float4 x3 = *(const float4*)&xs[(kk + 3) * 36 + bb0];
#pragma unroll
    for (int oo = 0; oo < 4; ++oo) {
      float4 wv = *(const float4*)(wp + oo * 1024 + kk);
      acc[oo][0] = fmaf(wv.x, x0.x, fmaf(wv.y, x1.x, fmaf(wv.z, x2.x, fmaf(wv.w, x3.x, acc[oo][0]))));
      acc[oo][1] = fmaf(wv.x, x0.y, fmaf(wv.y, x1.y, fmaf(wv.z, x2.y, fmaf(wv.w, x3.y, acc[oo][1]))));
      acc[oo][2] = fmaf(wv.x, x0.z, fmaf(wv.y, x1.z, fmaf(wv.z, x2.z, fmaf(wv.w, x3.z, acc[oo][2]))));
      acc[oo][3] = fmaf(wv.x, x0.w, fmaf(wv.y, x1.w, fmaf(wv.z, x2.w, fmaf(wv.w, x3.w, acc[oo][3]))));
    }
  }
#pragma unroll
  for (int bi = 0; bi < 4; ++bi) {
    float4 rv = make_float4(acc[0][bi], acc[1][bi], acc[2][bi], acc[3][bi]);
    *(float4*)&pout[(ksp * 32 + bb0 + bi) * 1024 + o] = rv;
  }
}

// ---------------- tail1 (per batch): h,t from partials; LN+ELU+residual; ff2; gates; moe stage0 pre-bn ----------------
__global__ __launch_bounds__(256) void k_tail1(
    const float* __restrict__ pfc, const float* __restrict__ fcb,
    const float* __restrict__ pff1, const float* __restrict__ ff1b,
    const float* __restrict__ lng, const float* __restrict__ lnb,
    const float* __restrict__ f2w, const float* __restrict__ f2b,
    const float* __restrict__ vp, const float* __restrict__ w0,
    const float* __restrict__ b0, float* __restrict__ wgate,
    float* __restrict__ s1pre) {
  __shared__ float hs[1024], ts[1024];
  __shared__ float mw_s[48];
  __shared__ float red2[4][2];
  __shared__ float bc[2];
  __shared__ float tot_s;
  const int b = blockIdx.x, tid = threadIdx.x;
  const int lane = tid & 63, wid = tid >> 6;
  for (int o = tid; o < 1024; o += 256) {
    float hv = fcb[o];
#pragma unroll 4
    for (int j = 0; j < 32; ++j) hv += pfc[(j * 32 + b) * 1024 + o];
    hs[o] = hv;
    float tv = ff1b[o];
#pragma unroll 4
    for (int j = 0; j < 16; ++j) tv += pff1[(j * 32 + b) * 1024 + o];
    ts[o] = tv;
  }
  __syncthreads();
  float ls = 0.f, lss = 0.f;
  for (int o = tid; o < 1024; o += 256) {
    float t = ts[o];
    ls += t; lss += t * t;
  }
  ls = wred(ls); lss = wred(lss);
  if (lane == 0) { red2[wid][0] = ls; red2[wid][1] = lss; }
  __syncthreads();
  if (tid == 0) {
    float S = red2[0][0] + red2[1][0] + red2[2][0] + red2[3][0];
    float SS = red2[0][1] + red2[1][1] + red2[2][1] + red2[3][1];
    float m = S * (1.f / 1024.f);
    float var = SS * (1.f / 1024.f) - m * m;
    bc[0] = m; bc[1] = rsqrtf(var + EPSF);
  }
  __syncthreads();
  const float m = bc[0], inv = bc[1];
  for (int o = tid; o < 1024; o += 256) {
    float y = fmaf((ts[o] - m) * inv, lng[o], lnb[o]);
    float e = (y > 0.f) ? y : expm1f(y);
    ts[o] = hs[o] + e;  // h2
  }
  __syncthreads();
  if (tid < 192) {
    int e = tid >> 2, part = tid & 3;
    float acc = 0.f;
    for (int o = part; o < 1024; o += 4) acc = fmaf(f2w[e * 1024 + o], ts[o], acc);
    acc += __shfl_down(acc, 1, 64);
    acc += __shfl_down(acc, 2, 64);
    if (part == 0) mw_s[e] = acc + f2b[e];
  }
  __syncthreads();
  if (tid < 64) {
    float v = (tid < 48) ? mw_s[tid] : 0.f;
    float t = wred(v);
    if (tid == 0) tot_s = t;
  }
  __syncthreads();
  if (tid < 48) {
    float wg = mw_s[tid] / tot_s;
    mw_s[tid] = wg;
    wgate[b * 48 + tid] = wg;
  }
  __syncthreads();
  if (tid < 32) {
    const int o = tid;
    const float v0 = vp[b * 3], v1 = vp[b * 3 + 1], v2 = vp[b * 3 + 2];
    float acc = 0.f;
#pragma unroll 4
    for (int e = 0; e < 48; ++e) {
      const float* wr = w0 + (e * 32 + o) * 3;
      float y = b0[e * 32 + o] + wr[0] * v0 + wr[1] * v1 + wr[2] * v2;
      acc = fmaf(mw_s[e], y, acc);
    }
    s1pre[b * 32 + o] = acc;
  }
}

// ---------------- moe1 (per batch): bn over batch (redundant) + prelu + gated expert layer 1 ----------------
__global__ __launch_bounds__(128) void k_moe1(
    const float* __restrict__ s1pre, const float* __restrict__ g0,
    const float* __restrict__ be0, const float* __restrict__ pf_p,
    const float* __restrict__ wgate, const float* __restrict__ w1,
    const float* __restrict__ b1, float* __restrict__ s2pre) {
  __shared__ float s1n[32];
  __shared__ float wg[48];
  const int b = blockIdx.x, tid = threadIdx.x;
  const float pf = pf_p[0];
  if (tid < 48) wg[tid] = wgate[b * 48 + tid];
  if (tid < 32) {
    const int o = tid;
    float s = 0.f, ss = 0.f;
    for (int bb = 0; bb < 32; ++bb) {
      float v = s1pre[bb * 32 + o];
      s += v; ss += v * v;
    }
    float mm = s * (1.f / 32.f);
    float var = ss * (1.f / 32.f) - mm * mm;
    float a = g0[o] * rsqrtf(var + EPSF);
    float c = be0[o] - mm * a;
    float v = fmaf(s1pre[b * 32 + o], a, c);
    s1n[o] = (v >= 0.f) ? v : pf * v;
  }
  __syncthreads();
  const int op = tid;  // 0..127
  float acc = 0.f;
  for (int e = 0; e < 48; ++e) {
    const float* wr = w1 + (e * 128 + op) * 32;
    float y = b1[e * 128 + op];
#pragma unroll
    for (int i = 0; i < 32; i += 4) {
      float4 wv = *(const float4*)(wr + i);
      y = fmaf(wv.x, s1n[i], fmaf(wv.y, s1n[i + 1], fmaf(wv.z, s1n[i + 2], fmaf(wv.w, s1n[i + 3], y))));
    }
    acc = fmaf(wg[e], y, acc);
  }
  s2pre[b * 128 + op] = acc;
}

// ---------------- final: bn over batch + prelu + dot(128) + sigmoid ----------------
__global__ __launch_bounds__(256) void k_final(
    const float* __restrict__ s2pre, const float* __restrict__ g1,
    const float* __restrict__ be1, const float* __restrict__ pf_p,
    const float* __restrict__ ow, const float* __restrict__ obp,
    float* __restrict__ outp) {
  __shared__ float s2[32 * 132];
  __shared__ float ca[128], cb[128];
  const int tid = threadIdx.x;
  for (int r = tid; r < 4096; r += 256) {
    int b = r >> 7, o = r & 127;
    s2[b * 132 + o] = s2pre[r];
  }
  __syncthreads();
  if (tid < 128) {
    const int o = tid;
    float s = 0.f, ss = 0.f;
    for (int b = 0; b < 32; ++b) {
      float v = s2[b * 132 + o];
      s += v; ss += v * v;
    }
    float mm = s * (1.f / 32.f);
    float var = ss * (1.f / 32.f) - mm * mm;
    float a = g1[o] * rsqrtf(var + EPSF);
    ca[o] = a; cb[o] = be1[o] - mm * a;
  }
  __syncthreads();
  const float pf = pf_p[0];
  if (tid < 32) {
    const int b = tid;
    float acc = 0.f;
#pragma unroll 4
    for (int o = 0; o < 128; ++o) {
      float v = fmaf(s2[b * 132 + o], ca[o], cb[o]);
      v = (v >= 0.f) ? v : pf * v;
      acc = fmaf(v, ow[o], acc);
    }
    float z = acc + obp[0];
    outp[b] = 1.f / (1.f + __expf(-z));
  }
}

// ---------------- launch ----------------
extern "C" void kernel_launch(void* const* d_in, const int* in_sizes, int n_in,
                              void* d_out, int out_size, void* d_ws, size_t ws_size,
                              hipStream_t stream) {
  (void)in_sizes; (void)n_in; (void)out_size; (void)ws_size;
  const float* vertex_pos = (const float*)d_in[0];
  const float* body_mesh  = (const float*)d_in[1];
  const float* conv1_w    = (const float*)d_in[2];
  const float* conv1_b    = (const float*)d_in[3];
  const float* bn1_g      = (const float*)d_in[4];
  const float* bn1_b      = (const float*)d_in[5];
  const float* conv2_w    = (const float*)d_in[6];
  const float* conv2_b    = (const float*)d_in[7];
  const float* bn2_g      = (const float*)d_in[8];
  const float* bn2_b      = (const float*)d_in[9];
  const float* prelu_a    = (const float*)d_in[10];
  const float* wq = (const float*)d_in[11]; const float* bq = (const float*)d_in[12];
  const float* wk = (const float*)d_in[13]; const float* bk = (const float*)d_in[14];
  const float* wv = (const float*)d_in[15]; const float* bv = (const float*)d_in[16];
  const float* fc_w  = (const float*)d_in[17]; const float* fc_b  = (const float*)d_in[18];
  const float* ff1_w = (const float*)d_in[19]; const float* ff1_b = (const float*)d_in[20];
  const float* ln_g  = (const float*)d_in[21]; const float* ln_b  = (const float*)d_in[22];
  const float* ff2_w = (const float*)d_in[23]; const float* ff2_b = (const float*)d_in[24];
  const float* fus_w0 = (const float*)d_in[25]; const float* fus_b0 = (const float*)d_in[26];
  const float* fus_w1 = (const float*)d_in[27]; const float* fus_b1 = (const float*)d_in[28];
  const float* bnf0_g = (const float*)d_in[29]; const float* bnf0_b = (const float*)d_in[30];
  const float* bnf1_g = (const float*)d_in[31]; const float* bnf1_b = (const float*)d_in[32];
  const float* prelu_f = (const float*)d_in[33];
  const float* out_w = (const float*)d_in[34]; const float* out_b = (const float*)d_in[35];

  float* ws = (float*)d_ws;
  // region A [0, 1048576): conv1_out / conv2_out / q / k / v  -- later overlaid by p_fc
  float* conv1_out = ws + 0;        // 326496
  float* conv2_out = ws + 326496;   // 294912 -> 621408
  float* qws = ws + 621408;         // 131072 -> 752480
  float* kws = ws + 752480;         // 131072 -> 883552
  float* vws = ws + 883552;         // 131072 -> 1014624
  float* p_fc = ws + 0;             // 1048576 (overlays region A; all dead by k_fc)
  float* av    = ws + 1048576;      // 131072 -> 1179648
  float* p_ff1 = ws + 1179648;      // 524288 -> 1703936
  float* part1 = ws + 1703936;      // 2688   -> 1706624
  float* part2 = ws + 1706624;      // 2304   -> 1708928
  float* wgate = ws + 1708928;      // 1536   -> 1710464
  float* s1pre = ws + 1710464;      // 1024   -> 1711488
  float* s2pre = ws + 1711488;      // 4096   -> 1715584 floats (~6.9 MB)

  k_conv1<<<448, 256, 0, stream>>>(body_mesh, conv1_w, conv1_b, conv1_out, part1);
  k_conv2<<<384, 256, 0, stream>>>(conv1_out, part1, bn1_g, bn1_b, conv2_w, conv2_b, conv2_out, part2);
  k_qkv<<<128, 256, 0, stream>>>(conv2_out, part2, bn2_g, bn2_b, prelu_a,
                                 wq, bq, wk, bk, wv, bv, qws, kws, vws);
  k_attn<<<256, 256, 0, stream>>>(qws, kws, vws, av);
  k_fc<<<256, 256, 0, stream>>>(av, fc_w, p_fc);
  k_ff1<<<128, 256, 0, stream>>>(p_fc, fc_b, ff1_w, p_ff1);
  k_tail1<<<32, 256, 0, stream>>>(p_fc, fc_b, p_ff1, ff1_b, ln_g, ln_b, ff2_w, ff2_b,
                                  vertex_pos, fus_w0, fus_b0, wgate, s1pre);
  k_moe1<<<32, 128, 0, stream>>>(s1pre, bnf0_g, bnf0_b, prelu_f, wgate, fus_w1, fus_b1, s2pre);
  k_final<<<1, 256, 0, stream>>>(s2pre, bnf1_g, bnf1_b, prelu_f, out_w, out_b, (float*)d_out);
}

// Round 2
// 372.137 us; speedup vs baseline: 1.3472x; 1.3472x over previous
//
#include <hip/hip_runtime.h>

#define EPSF 1e-5f

// ---------------- helpers ----------------
__device__ __forceinline__ float wred(float v) {
#pragma unroll
  for (int off = 32; off > 0; off >>= 1) v += __shfl_down(v, off, 64);
  return v;
}

// ---------------- conv1: [32,1,20813,3] * [3,1,409,3] s=(6,1) -> [32,3,3401] + stats ----------------
// out[c][oh] = sum_i w[c][i] * mesh[oh*18 + i], i<1227. 128 outputs/block, 2-way K-split.
__global__ __launch_bounds__(256) void k_conv1(
    const float* __restrict__ mesh, const float* __restrict__ cw,
    const float* __restrict__ cb, float* __restrict__ out,
    float* __restrict__ part) {
  __shared__ float wsm[3684];   // 3 rows x 1228 (padded to even)
  __shared__ float sm[3513];    // (127*18 + 1227)
  __shared__ float pm[384];
  __shared__ float redm[4][6];
  const int tid = threadIdx.x;
  const int tile = blockIdx.x % 27, b = blockIdx.x / 27;
  const int oh0 = tile << 7;
  const int nvalid = min(128, 3401 - oh0);
  const int nload = (nvalid - 1) * 18 + 1227;
  // stage weights (padded rows of 1228)
  for (int j = tid; j < 3681; j += 256) {
    int c = (j >= 2454) ? 2 : ((j >= 1227) ? 1 : 0);
    wsm[c * 1228 + (j - c * 1227)] = cw[j];
  }
  // stage mesh tile
  const float* src = mesh + b * 62439 + oh0 * 18;
  for (int j = tid; j < nload; j += 256) sm[j] = src[j];
  __syncthreads();
  const int half = tid >> 7, oidx = tid & 127;
  const float* xp = sm + oidx * 18;
  const int i0 = half ? 614 : 0, i1 = half ? 1226 : 614;
  float a0 = 0.f, a1 = 0.f, a2 = 0.f;
#pragma unroll 4
  for (int i = i0; i < i1; i += 2) {
    float2 x = *(const float2*)(xp + i);
    float2 w0 = *(const float2*)(wsm + i);
    float2 w1 = *(const float2*)(wsm + 1228 + i);
    float2 w2 = *(const float2*)(wsm + 2456 + i);
    a0 = fmaf(w0.x, x.x, fmaf(w0.y, x.y, a0));
    a1 = fmaf(w1.x, x.x, fmaf(w1.y, x.y, a1));
    a2 = fmaf(w2.x, x.x, fmaf(w2.y, x.y, a2));
  }
  if (half) {
    float x = xp[1226];
    a0 = fmaf(wsm[1226], x, a0);
    a1 = fmaf(wsm[1228 + 1226], x, a1);
    a2 = fmaf(wsm[2456 + 1226], x, a2);
    pm[oidx] = a0; pm[128 + oidx] = a1; pm[256 + oidx] = a2;
  }
  __syncthreads();
  float st[6] = {0.f, 0.f, 0.f, 0.f, 0.f, 0.f};
  if (!half && oidx < nvalid) {
    a0 += pm[oidx] + cb[0];
    a1 += pm[128 + oidx] + cb[1];
    a2 += pm[256 + oidx] + cb[2];
    float* op = out + b * 10203 + oh0 + oidx;
    op[0] = a0; op[3401] = a1; op[6802] = a2;
    st[0] = a0; st[1] = a0 * a0; st[2] = a1; st[3] = a1 * a1; st[4] = a2; st[5] = a2 * a2;
  }
  const int lane = tid & 63, wid = tid >> 6;
#pragma unroll
  for (int c = 0; c < 6; ++c) {
    float rv = wred(st[c]);
    if (lane == 0) redm[wid][c] = rv;
  }
  __syncthreads();
  if (tid < 6)
    part[blockIdx.x * 6 + tid] = redm[0][tid] + redm[1][tid] + redm[2][tid] + redm[3][tid];
}

// ---------------- conv2: bn1(conv1) reshaped, 990-tap stride-3 -> [32,3,3072] + stats ----------------
__global__ __launch_bounds__(256) void k_conv2(
    const float* __restrict__ x1, const float* __restrict__ part1,
    const float* __restrict__ g1, const float* __restrict__ be1,
    const float* __restrict__ cw, const float* __restrict__ cb,
    float* __restrict__ out, float* __restrict__ part) {
  __shared__ float wsm[2970];
  __shared__ float sm[1371];   // 127*3 + 990
  __shared__ float pm[384];
  __shared__ float redm[4][6];
  __shared__ float coef[6];
  const int tid = threadIdx.x;
  const int lane = tid & 63, wid = tid >> 6;
  {  // reduce conv1 stats (864 blocks x 6) -> bn1 coefficients
    float r[6] = {0.f, 0.f, 0.f, 0.f, 0.f, 0.f};
    for (int j = tid; j < 864; j += 256) {
#pragma unroll
      for (int c = 0; c < 6; ++c) r[c] += part1[j * 6 + c];
    }
#pragma unroll
    for (int c = 0; c < 6; ++c) {
      float rv = wred(r[c]);
      if (lane == 0) redm[wid][c] = rv;
    }
    __syncthreads();
    if (tid == 0) {
      const float inv_n = 1.f / (32.f * 3401.f);
#pragma unroll
      for (int c = 0; c < 3; ++c) {
        float s = redm[0][2 * c] + redm[1][2 * c] + redm[2][2 * c] + redm[3][2 * c];
        float ss = redm[0][2 * c + 1] + redm[1][2 * c + 1] + redm[2][2 * c + 1] + redm[3][2 * c + 1];
        float m = s * inv_n;
        float var = ss * inv_n - m * m;
        float a = g1[c] * rsqrtf(var + EPSF);
        coef[c] = a; coef[3 + c] = be1[c] - m * a;
      }
    }
  }
  for (int j = tid; j < 2970; j += 256) wsm[j] = cw[j];
  __syncthreads();  // covers coef + wsm
  const int tile = blockIdx.x % 24, b = blockIdx.x / 24;
  const int oh0 = tile << 7;
  const int g0 = oh0 * 3;
  const float* src = x1 + b * 10203 + g0;
  for (int j = tid; j < 1371; j += 256) {
    int gg = g0 + j;
    int c = (gg >= 6802) ? 2 : ((gg >= 3401) ? 1 : 0);
    sm[j] = fmaf(coef[c], src[j], coef[3 + c]);
  }
  __syncthreads();
  const int half = tid >> 7, oidx = tid & 127;
  const float* xp = sm + oidx * 3;
  const int i0 = half ? 496 : 0, i1 = half ? 990 : 496;
  float a0 = 0.f, a1 = 0.f, a2 = 0.f;
#pragma unroll 4
  for (int i = i0; i < i1; i += 2) {
    float x0 = xp[i], x1v = xp[i + 1];
    float2 w0 = *(const float2*)(wsm + i);
    float2 w1 = *(const float2*)(wsm + 990 + i);
    float2 w2 = *(const float2*)(wsm + 1980 + i);
    a0 = fmaf(w0.x, x0, fmaf(w0.y, x1v, a0));
    a1 = fmaf(w1.x, x0, fmaf(w1.y, x1v, a1));
    a2 = fmaf(w2.x, x0, fmaf(w2.y, x1v, a2));
  }
  if (half) { pm[oidx] = a0; pm[128 + oidx] = a1; pm[256 + oidx] = a2; }
  __syncthreads();
  float st[6] = {0.f, 0.f, 0.f, 0.f, 0.f, 0.f};
  if (!half) {
    a0 += pm[oidx] + cb[0];
    a1 += pm[128 + oidx] + cb[1];
    a2 += pm[256 + oidx] + cb[2];
    float* op = out + b * 9216 + oh0 + oidx;
    op[0] = a0; op[3072] = a1; op[6144] = a2;
    st[0] = a0; st[1] = a0 * a0; st[2] = a1; st[3] = a1 * a1; st[4] = a2; st[5] = a2 * a2;
  }
  __syncthreads();
#pragma unroll
  for (int c = 0; c < 6; ++c) {
    float rv = wred(st[c]);
    if (lane == 0) redm[wid][c] = rv;
  }
  __syncthreads();
  if (tid < 6)
    part[blockIdx.x * 6 + tid] = redm[0][tid] + redm[1][tid] + redm[2][tid] + redm[3][tid];
}

// ---------------- qkv: bn2 + prelu + 3x (9->4) ; q scaled by 1/sqrt(2)*log2(e) ----------------
__global__ __launch_bounds__(256) void k_qkv(
    const float* __restrict__ x2, const float* __restrict__ part2,
    const float* __restrict__ g2, const float* __restrict__ be2,
    const float* __restrict__ pa_p,
    const float* __restrict__ wq, const float* __restrict__ bq,
    const float* __restrict__ wk, const float* __restrict__ bk,
    const float* __restrict__ wv, const float* __restrict__ bv,
    float* __restrict__ qo, float* __restrict__ ko, float* __restrict__ vo) {
  __shared__ float redm[4][6];
  __shared__ float coef[6];
  const int tid = threadIdx.x;
  const int lane = tid & 63, wid = tid >> 6;
  {
    float r[6] = {0.f, 0.f, 0.f, 0.f, 0.f, 0.f};
    for (int j = tid; j < 768; j += 256) {
#pragma unroll
      for (int c = 0; c < 6; ++c) r[c] += part2[j * 6 + c];
    }
#pragma unroll
    for (int c = 0; c < 6; ++c) {
      float rv = wred(r[c]);
      if (lane == 0) redm[wid][c] = rv;
    }
    __syncthreads();
    if (tid == 0) {
      const float inv_n = 1.f / (32.f * 3072.f);
#pragma unroll
      for (int c = 0; c < 3; ++c) {
        float s = redm[0][2 * c] + redm[1][2 * c] + redm[2][2 * c] + redm[3][2 * c];
        float ss = redm[0][2 * c + 1] + redm[1][2 * c + 1] + redm[2][2 * c + 1] + redm[3][2 * c + 1];
        float m = s * inv_n;
        float var = ss * inv_n - m * m;
        float a = g2[c] * rsqrtf(var + EPSF);
        coef[c] = a; coef[3 + c] = be2[c] - m * a;
      }
    }
    __syncthreads();
  }
  const float pa = pa_p[0];
  const int id = blockIdx.x * 256 + tid;
  const int b = id >> 10, f = id & 1023;
  const float* src = x2 + b * 9216 + f * 9;
  float x[9];
  const int z0 = f * 9;
#pragma unroll
  for (int j = 0; j < 9; ++j) {
    int z = z0 + j;
    int c = (z >= 6144) ? 2 : ((z >= 3072) ? 1 : 0);
    float v = fmaf(coef[c], src[j], coef[3 + c]);
    x[j] = (v >= 0.f) ? v : pa * v;
  }
  const float QSCALE = 0.70710678118654752f * 1.44269504088896341f;  // 1/sqrt(HD) * log2(e)
#pragma unroll
  for (int dd = 0; dd < 4; ++dd) {
    float q = bq[dd], k = bk[dd], v = bv[dd];
#pragma unroll
    for (int j = 0; j < 9; ++j) {
      q = fmaf(wq[dd * 9 + j], x[j], q);
      k = fmaf(wk[dd * 9 + j], x[j], k);
      v = fmaf(wv[dd * 9 + j], x[j], v);
    }
    int hh = dd >> 1, d = dd & 1;
    int idx = ((b * 2 + hh) * 1024 + f) * 2 + d;
    qo[idx] = q * QSCALE;
    ko[idx] = k;
    vo[idx] = v;
  }
}

// ---------------- attention: per (b,h) softmax(qk)v, HD=2; bound-max single pass ----------------
// grid 512 = 64 bh x 8 row-blocks; thread = 4 rows x 128 keys; 8 lanes per row-group.
__device__ __forceinline__ int kvIdx(int j) { return j + (j >> 7); }  // pad: bank-conflict-free key slices

__global__ __launch_bounds__(256) void k_attn(
    const float* __restrict__ q, const float* __restrict__ k,
    const float* __restrict__ v, float* __restrict__ av) {
  __shared__ float4 kv[1032];
  __shared__ float smax[4];
  const int tid = threadIdx.x;
  const int bh = blockIdx.x >> 3, rblk = blockIdx.x & 7;
  const float2* kp = (const float2*)(k + bh * 2048);
  const float2* vp = (const float2*)(v + bh * 2048);
  float nkm = 0.f;
  for (int j = tid; j < 1024; j += 256) {
    float2 kk = kp[j], vv = vp[j];
    kv[kvIdx(j)] = make_float4(kk.x, kk.y, vv.x, vv.y);
    nkm = fmaxf(nkm, fmaf(kk.x, kk.x, kk.y * kk.y));
  }
#pragma unroll
  for (int off = 32; off > 0; off >>= 1) nkm = fmaxf(nkm, __shfl_xor(nkm, off, 64));
  if ((tid & 63) == 0) smax[tid >> 6] = nkm;
  __syncthreads();
  const float knorm = sqrtf(fmaxf(fmaxf(smax[0], smax[1]), fmaxf(smax[2], smax[3])));
  const int lane = tid & 63, w = tid >> 6;
  const int rg = (w << 3) | (lane >> 3);  // 0..31 row-group in block
  const int ks = lane & 7;                // key slice
  const int r0 = rblk * 128 + rg * 4;
  const float4 q01 = *(const float4*)(q + (bh * 1024 + r0) * 2);
  const float4 q23 = *(const float4*)(q + (bh * 1024 + r0) * 2 + 4);
  float qx[4] = {q01.x, q01.z, q23.x, q23.z};
  float qy[4] = {q01.y, q01.w, q23.y, q23.w};
  float m[4], l[4] = {0.f, 0.f, 0.f, 0.f};
  float o0[4] = {0.f, 0.f, 0.f, 0.f}, o1[4] = {0.f, 0.f, 0.f, 0.f};
#pragma unroll
  for (int r = 0; r < 4; ++r) m[r] = sqrtf(fmaf(qx[r], qx[r], qy[r] * qy[r])) * knorm;
  const int j0 = ks * 128;
#pragma unroll 4
  for (int jj = 0; jj < 128; ++jj) {
    float4 kk = kv[kvIdx(j0 + jj)];
#pragma unroll
    for (int r = 0; r < 4; ++r) {
      float s = fmaf(qx[r], kk.x, qy[r] * kk.y);
      float p = exp2f(s - m[r]);  // q pre-scaled to exp2 space; s<=m guaranteed
      l[r] += p;
      o0[r] = fmaf(p, kk.z, o0[r]);
      o1[r] = fmaf(p, kk.w, o1[r]);
    }
  }
#pragma unroll
  for (int off = 1; off <= 4; off <<= 1) {
#pragma unroll
    for (int r = 0; r < 4; ++r) {
      l[r] += __shfl_xor(l[r], off, 64);
      o0[r] += __shfl_xor(o0[r], off, 64);
      o1[r] += __shfl_xor(o1[r], off, 64);
    }
  }
  if (ks == 0) {
    const int b = bh >> 1, hh = bh & 1;
#pragma unroll
    for (int r = 0; r < 4; ++r) {
      float rl = 1.f / l[r];
      *(float2*)(av + b * 4096 + (r0 + r) * 4 + hh * 2) = make_float2(o0[r] * rl, o1[r] * rl);
    }
  }
}

// ---------------- fc: [32,4096] x [1024,4096]^T, K-split partials ----------------
__global__ __launch_bounds__(256) void k_fc(
    const float* __restrict__ x, const float* __restrict__ w,
    float* __restrict__ pout) {
  __shared__ float xs[128 * 36];
  const int tid = threadIdx.x;
  const int ob = blockIdx.x & 7, ksp = blockIdx.x >> 3;
  const int k0 = ksp * 128, obase = ob * 128;
  for (int r = tid; r < 4096; r += 256) {
    int b = r >> 7, kk = r & 127;
    xs[kk * 36 + b] = x[b * 4096 + k0 + kk];
  }
  __syncthreads();
  const int og = tid & 31, bg = tid >> 5;
  const int o = obase + og * 4, bb0 = bg * 4;
  float acc[4][4] = {};
  const float* wp = w + o * 4096 + k0;
  for (int kk = 0; kk < 128; kk += 4) {
    float4 x0 = *(const float4*)&xs[(kk + 0) * 36 + bb0];
    float4 x1 = *(const float4*)&xs[(kk + 1) * 36 + bb0];
    float4 x2 = *(const float4*)&xs[(kk + 2) * 36 + bb0];
    float4 x3 = *(const float4*)&xs[(kk + 3) * 36 + bb0];
#pragma unroll
    for (int oo = 0; oo < 4; ++oo) {
      float4 wv = *(const float4*)(wp + oo * 4096 + kk);
      acc[oo][0] = fmaf(wv.x, x0.x, fmaf(wv.y, x1.x, fmaf(wv.z, x2.x, fmaf(wv.w, x3.x, acc[oo][0]))));
      acc[oo][1] = fmaf(wv.x, x0.y, fmaf(wv.y, x1.y, fmaf(wv.z, x2.y, fmaf(wv.w, x3.y, acc[oo][1]))));
      acc[oo][2] = fmaf(wv.x, x0.z, fmaf(wv.y, x1.z, fmaf(wv.z, x2.z, fmaf(wv.w, x3.z, acc[oo][2]))));
      acc[oo][3] = fmaf(wv.x, x0.w, fmaf(wv.y, x1.w, fmaf(wv.z, x2.w, fmaf(wv.w, x3.w, acc[oo][3]))));
    }
  }
#pragma unroll
  for (int bi = 0; bi < 4; ++bi) {
    float4 rv = make_float4(acc[0][bi], acc[1][bi], acc[2][bi], acc[3][bi]);
    *(float4*)&pout[(ksp * 32 + bb0 + bi) * 1024 + o] = rv;
  }
}

// ---------------- ff1: h=reduce(p_fc)+fc_b on the fly; [32,1024]x[1024,1024]^T ----------------
__global__ __launch_bounds__(256) void k_ff1(
    const float* __restrict__ pfc, const float* __restrict__ fcb,
    const float* __restrict__ w, float* __restrict__ pout) {
  __shared__ float xs[64 * 36];
  const int tid = threadIdx.x;
  const int ob = blockIdx.x & 7, ksp = blockIdx.x >> 3;
  const int k0 = ksp * 64, obase = ob * 128;
  for (int r = tid; r < 2048; r += 256) {
    int b = r >> 6, kk = r & 63;
    float hv = fcb[k0 + kk];
#pragma unroll 4
    for (int j = 0; j < 32; ++j) hv += pfc[(j * 32 + b) * 1024 + k0 + kk];
    xs[kk * 36 + b] = hv;
  }
  __syncthreads();
  const int og = tid & 31, bg = tid >> 5;
  const int o = obase + og * 4, bb0 = bg * 4;
  float acc[4][4] = {};
  const float* wp = w + o * 1024 + k0;
  for (int kk = 0; kk < 64; kk += 4) {
    float4 x0 = *(const float4*)&xs[(kk + 0) * 36 + bb0];
    float4 x1 = *(const float4*)&xs[(kk + 1) * 36 + bb0];
    float4 x2 = *(const float4*)&xs[(kk + 2) * 36 + bb0];
    float4 x3 = *(const float4*)&xs[(kk + 3) * 36 + bb0];
#pragma unroll
    for (int oo = 0; oo < 4; ++oo) {
      float4 wv = *(const float4*)(wp + oo * 1024 + kk);
      acc[oo][0] = fmaf(wv.x, x0.x, fmaf(wv.y, x1.x, fmaf(wv.z, x2.x, fmaf(wv.w, x3.x, acc[oo][0]))));
      acc[oo][1] = fmaf(wv.x, x0.y, fmaf(wv.y, x1.y, fmaf(wv.z, x2.y, fmaf(wv.w, x3.y, acc[oo][1]))));
      acc[oo][2] = fmaf(wv.x, x0.z, fmaf(wv.y, x1.z, fmaf(wv.z, x2.z, fmaf(wv.w, x3.z, acc[oo][2]))));
      acc[oo][3] = fmaf(wv.x, x0.w, fmaf(wv.y, x1.w, fmaf(wv.z, x2.w, fmaf(wv.w, x3.w, acc[oo][3]))));
    }
  }
#pragma unroll
  for (int bi = 0; bi < 4; ++bi) {
    float4 rv = make_float4(acc[0][bi], acc[1][bi], acc[2][bi], acc[3][bi]);
    *(float4*)&pout[(ksp * 32 + bb0 + bi) * 1024 + o] = rv;
  }
}

// ---------------- tail1 (per batch): h,t; LN+ELU+residual; ff2; gates; moe stage0 pre-bn ----------------
__global__ __launch_bounds__(256) void k_tail1(
    const float* __restrict__ pfc, const float* __restrict__ fcb,
    const float* __restrict__ pff1, const float* __restrict__ ff1b,
    const float* __restrict__ lng, const float* __restrict__ lnb,
    const float* __restrict__ f2w, const float* __restrict__ f2b,
    const float* __restrict__ vp, const float* __restrict__ w0,
    const float* __restrict__ b0, float* __restrict__ wgate,
    float* __restrict__ s1pre) {
  __shared__ float hs[1024], ts[1024];
  __shared__ float mw_s[48];
  __shared__ float red2[4][2];
  __shared__ float bc[2];
  __shared__ float tot_s;
  const int b = blockIdx.x, tid = threadIdx.x;
  const int lane = tid & 63, wid = tid >> 6;
  for (int o = tid; o < 1024; o += 256) {
    float hv = fcb[o];
#pragma unroll 4
    for (int j = 0; j < 32; ++j) hv += pfc[(j * 32 + b) * 1024 + o];
    hs[o] = hv;
    float tv = ff1b[o];
#pragma unroll 4
    for (int j = 0; j < 16; ++j) tv += pff1[(j * 32 + b) * 1024 + o];
    ts[o] = tv;
  }
  __syncthreads();
  float ls = 0.f, lss = 0.f;
  for (int o = tid; o < 1024; o += 256) {
    float t = ts[o];
    ls += t; lss += t * t;
  }
  ls = wred(ls); lss = wred(lss);
  if (lane == 0) { red2[wid][0] = ls; red2[wid][1] = lss; }
  __syncthreads();
  if (tid == 0) {
    float S = red2[0][0] + red2[1][0] + red2[2][0] + red2[3][0];
    float SS = red2[0][1] + red2[1][1] + red2[2][1] + red2[3][1];
    float m = S * (1.f / 1024.f);
    float var = SS * (1.f / 1024.f) - m * m;
    bc[0] = m; bc[1] = rsqrtf(var + EPSF);
  }
  __syncthreads();
  const float m = bc[0], inv = bc[1];
  for (int o = tid; o < 1024; o += 256) {
    float y = fmaf((ts[o] - m) * inv, lng[o], lnb[o]);
    float e = (y > 0.f) ? y : expm1f(y);
    ts[o] = hs[o] + e;  // h2
  }
  __syncthreads();
  if (tid < 192) {
    int e = tid >> 2, part = tid & 3;
    float acc = 0.f;
    const float* wr = f2w + e * 1024 + part * 4;
    for (int i = 0; i < 64; ++i) {
      float4 wv = *(const float4*)(wr + i * 16);
      int ob = i * 16 + part * 4;
      acc = fmaf(wv.x, ts[ob], fmaf(wv.y, ts[ob + 1], fmaf(wv.z, ts[ob + 2], fmaf(wv.w, ts[ob + 3], acc))));
    }
    acc += __shfl_down(acc, 1, 64);
    acc += __shfl_down(acc, 2, 64);
    if (part == 0) mw_s[e] = acc + f2b[e];
  }
  __syncthreads();
  if (tid < 64) {
    float v = (tid < 48) ? mw_s[tid] : 0.f;
    float t = wred(v);
    if (tid == 0) tot_s = t;
  }
  __syncthreads();
  if (tid < 48) {
    float wg = mw_s[tid] / tot_s;
    mw_s[tid] = wg;
    wgate[b * 48 + tid] = wg;
  }
  __syncthreads();
  if (tid < 32) {
    const int o = tid;
    const float v0 = vp[b * 3], v1 = vp[b * 3 + 1], v2 = vp[b * 3 + 2];
    float acc = 0.f;
#pragma unroll 4
    for (int e = 0; e < 48; ++e) {
      const float* wr = w0 + (e * 32 + o) * 3;
      float y = b0[e * 32 + o] + wr[0] * v0 + wr[1] * v1 + wr[2] * v2;
      acc = fmaf(mw_s[e], y, acc);
    }
    s1pre[b * 32 + o] = acc;
  }
}

// ---------------- moe1 (per batch): bn over batch (redundant) + prelu + gated expert layer 1 ----------------
__global__ __launch_bounds__(128) void k_moe1(
    const float* __restrict__ s1pre, const float* __restrict__ g0,
    const float* __restrict__ be0, const float* __restrict__ pf_p,
    const float* __restrict__ wgate, const float* __restrict__ w1,
    const float* __restrict__ b1, float* __restrict__ s2pre) {
  __shared__ float s1n[32];
  __shared__ float wg[48];
  const int b = blockIdx.x, tid = threadIdx.x;
  const float pf = pf_p[0];
  if (tid < 48) wg[tid] = wgate[b * 48 + tid];
  if (tid < 32) {
    const int o = tid;
    float s = 0.f, ss = 0.f;
    for (int bb = 0; bb < 32; ++bb) {
      float v = s1pre[bb * 32 + o];
      s += v; ss += v * v;
    }
    float mm = s * (1.f / 32.f);
    float var = ss * (1.f / 32.f) - mm * mm;
    float a = g0[o] * rsqrtf(var + EPSF);
    float c = be0[o] - mm * a;
    float v = fmaf(s1pre[b * 32 + o], a, c);
    s1n[o] = (v >= 0.f) ? v : pf * v;
  }
  __syncthreads();
  const int op = tid;  // 0..127
  float acc = 0.f;
  for (int e = 0; e < 48; ++e) {
    const float* wr = w1 + (e * 128 + op) * 32;
    float y = b1[e * 128 + op];
#pragma unroll
    for (int i = 0; i < 32; i += 4) {
      float4 wv = *(const float4*)(wr + i);
      y = fmaf(wv.x, s1n[i], fmaf(wv.y, s1n[i + 1], fmaf(wv.z, s1n[i + 2], fmaf(wv.w, s1n[i + 3], y))));
    }
    acc = fmaf(wg[e], y, acc);
  }
  s2pre[b * 128 + op] = acc;
}

// ---------------- final: bn over batch + prelu + dot(128) + sigmoid ----------------
__global__ __launch_bounds__(256) void k_final(
    const float* __restrict__ s2pre, const float* __restrict__ g1,
    const float* __restrict__ be1, const float* __restrict__ pf_p,
    const float* __restrict__ ow, const float* __restrict__ obp,
    float* __restrict__ outp) {
  __shared__ float s2[32 * 132];
  __shared__ float ca[128], cb[128];
  const int tid = threadIdx.x;
  for (int r = tid; r < 4096; r += 256) {
    int b = r >> 7, o = r & 127;
    s2[b * 132 + o] = s2pre[r];
  }
  __syncthreads();
  if (tid < 128) {
    const int o = tid;
    float s = 0.f, ss = 0.f;
    for (int b = 0; b < 32; ++b) {
      float v = s2[b * 132 + o];
      s += v; ss += v * v;
    }
    float mm = s * (1.f / 32.f);
    float var = ss * (1.f / 32.f) - mm * mm;
    float a = g1[o] * rsqrtf(var + EPSF);
    ca[o] = a; cb[o] = be1[o] - mm * a;
  }
  __syncthreads();
  const float pf = pf_p[0];
  if (tid < 32) {
    const int b = tid;
    float acc = 0.f;
#pragma unroll 4
    for (int o = 0; o < 128; ++o) {
      float v = fmaf(s2[b * 132 + o], ca[o], cb[o]);
      v = (v >= 0.f) ? v : pf * v;
      acc = fmaf(v, ow[o], acc);
    }
    float z = acc + obp[0];
    outp[b] = 1.f / (1.f + __expf(-z));
  }
}

// ---------------- launch ----------------
extern "C" void kernel_launch(void* const* d_in, const int* in_sizes, int n_in,
                              void* d_out, int out_size, void* d_ws, size_t ws_size,
                              hipStream_t stream) {
  (void)in_sizes; (void)n_in; (void)out_size; (void)ws_size;
  const float* vertex_pos = (const float*)d_in[0];
  const float* body_mesh  = (const float*)d_in[1];
  const float* conv1_w    = (const float*)d_in[2];
  const float* conv1_b    = (const float*)d_in[3];
  const float* bn1_g      = (const float*)d_in[4];
  const float* bn1_b      = (const float*)d_in[5];
  const float* conv2_w    = (const float*)d_in[6];
  const float* conv2_b    = (const float*)d_in[7];
  const float* bn2_g      = (const float*)d_in[8];
  const float* bn2_b      = (const float*)d_in[9];
  const float* prelu_a    = (const float*)d_in[10];
  const float* wq = (const float*)d_in[11]; const float* bq = (const float*)d_in[12];
  const float* wk = (const float*)d_in[13]; const float* bk = (const float*)d_in[14];
  const float* wv = (const float*)d_in[15]; const float* bv = (const float*)d_in[16];
  const float* fc_w  = (const float*)d_in[17]; const float* fc_b  = (const float*)d_in[18];
  const float* ff1_w = (const float*)d_in[19]; const float* ff1_b = (const float*)d_in[20];
  const float* ln_g  = (const float*)d_in[21]; const float* ln_b  = (const float*)d_in[22];
  const float* ff2_w = (const float*)d_in[23]; const float* ff2_b = (const float*)d_in[24];
  const float* fus_w0 = (const float*)d_in[25]; const float* fus_b0 = (const float*)d_in[26];
  const float* fus_w1 = (const float*)d_in[27]; const float* fus_b1 = (const float*)d_in[28];
  const float* bnf0_g = (const float*)d_in[29]; const float* bnf0_b = (const float*)d_in[30];
  const float* bnf1_g = (const float*)d_in[31]; const float* bnf1_b = (const float*)d_in[32];
  const float* prelu_f = (const float*)d_in[33];
  const float* out_w = (const float*)d_in[34]; const float* out_b = (const float*)d_in[35];

  float* ws = (float*)d_ws;
  // region A [0, 1048576): conv1_out / conv2_out / q / k / v  -- later overlaid by p_fc
  float* conv1_out = ws + 0;        // 326496
  float* conv2_out = ws + 326496;   // 294912 -> 621408
  float* qws = ws + 621408;         // 131072 -> 752480
  float* kws = ws + 752480;         // 131072 -> 883552
  float* vws = ws + 883552;         // 131072 -> 1014624
  float* p_fc = ws + 0;             // 1048576 (overlays region A; all dead by k_fc)
  float* av    = ws + 1048576;      // 131072 -> 1179648
  float* p_ff1 = ws + 1179648;      // 524288 -> 1703936
  float* part1 = ws + 1703936;      // 5184   -> 1709120  (864 blocks x 6)
  float* part2 = ws + 1709120;      // 4608   -> 1713728  (768 blocks x 6)
  float* wgate = ws + 1713728;      // 1536   -> 1715264
  float* s1pre = ws + 1715264;      // 1024   -> 1716288
  float* s2pre = ws + 1716288;      // 4096   -> 1720384 floats (~6.9 MB)

  k_conv1<<<864, 256, 0, stream>>>(body_mesh, conv1_w, conv1_b, conv1_out, part1);
  k_conv2<<<768, 256, 0, stream>>>(conv1_out, part1, bn1_g, bn1_b, conv2_w, conv2_b, conv2_out, part2);
  k_qkv<<<128, 256, 0, stream>>>(conv2_out, part2, bn2_g, bn2_b, prelu_a,
                                 wq, bq, wk, bk, wv, bv, qws, kws, vws);
  k_attn<<<512, 256, 0, stream>>>(qws, kws, vws, av);
  k_fc<<<256, 256, 0, stream>>>(av, fc_w, p_fc);
  k_ff1<<<128, 256, 0, stream>>>(p_fc, fc_b, ff1_w, p_ff1);
  k_tail1<<<32, 256, 0, stream>>>(p_fc, fc_b, p_ff1, ff1_b, ln_g, ln_b, ff2_w, ff2_b,
                                  vertex_pos, fus_w0, fus_b0, wgate, s1pre);
  k_moe1<<<32, 128, 0, stream>>>(s1pre, bnf0_g, bnf0_b, prelu_f, wgate, fus_w1, fus_b1, s2pre);
  k_final<<<1, 256, 0, stream>>>(s2pre, bnf1_g, bnf1_b, prelu_f, out_w, out_b, (float*)d_out);
}